// Round 5
// baseline (337.475 us; speedup 1.0000x reference)
//
#include <hip/hip_runtime.h>
#include <hip/hip_bf16.h>

typedef __attribute__((ext_vector_type(4))) float f32x4;
typedef __attribute__((ext_vector_type(16))) float f32x16;
typedef __attribute__((ext_vector_type(8))) short bf16x8;

#define IN_DIM 4096
#define OUT_DIM 4096
#define MROWS 8192   // B*S = 4*2048
#define NFREQ 8
#define TWO_PI 6.283185307179586f

#define BK 64
#define NT (IN_DIM / BK)        // 64 K-tiles
#define LDS_BUF 32768           // one operand buffer (256x64 bf16)
#define LDS_HALF 16384          // half buffer (128x64 bf16)
#define LDS_B_REGION 65536      // B region base byte

// f32 -> bf16 bits, round-to-nearest-even
__device__ __forceinline__ unsigned int f2bf(float f) {
    union { float f; unsigned int u; } a;
    a.f = f;
    unsigned int u = a.u;
    u += 0x7fffu + ((u >> 16) & 1u);
    return u >> 16;
}

// ---------------------------------------------------------------------------
// Fused prep kernel.
//  blocks [0, 4096):      dora rows — W_dora(bf16) = m*(W+irfft2(pad(delta)))/(||row||+eps)
//  blocks [4096, 20480):  x f32 -> bf16 cvt
// ---------------------------------------------------------------------------
#define ROT_C 0.9999988234517019f
#define ROT_S 0.0015339801862847655f

__global__ __launch_bounds__(256) void prep_kernel(
    const float* __restrict__ x,
    const float* __restrict__ W,
    const float* __restrict__ dre,
    const float* __restrict__ dimg,
    const float* __restrict__ mrow,
    unsigned short* __restrict__ Wd,
    unsigned short* __restrict__ xb)
{
    const int t = threadIdx.x;

    if (blockIdx.x >= OUT_DIM) {
        // ---- cvt branch ----
        const size_t idx = (size_t)(blockIdx.x - OUT_DIM) * 256 + t;
        const f32x4* p = (const f32x4*)(x + idx * 8);
        const f32x4 a = p[0], b = p[1];
        uint4 o;
        o.x = f2bf(a[0]) | (f2bf(a[1]) << 16);
        o.y = f2bf(a[2]) | (f2bf(a[3]) << 16);
        o.z = f2bf(b[0]) | (f2bf(b[1]) << 16);
        o.w = f2bf(b[2]) | (f2bf(b[3]) << 16);
        *(uint4*)(xb + idx * 8) = o;
        return;
    }

    // ---- dora branch ----
    const int o = blockIdx.x;

    float P[NFREQ], Q[NFREQ];
#pragma unroll
    for (int w = 0; w < NFREQ; ++w) { P[w] = 0.f; Q[w] = 0.f; }
#pragma unroll
    for (int h = 0; h < NFREQ; ++h) {
        const float th = (TWO_PI / 4096.0f) * (float)((h * o) & 4095);
        const float sh = __sinf(th), ch = __cosf(th);
#pragma unroll
        for (int w = 0; w < NFREQ; ++w) {
            const float A = 2.0f * dre[h * NFREQ + w];
            const float B = 2.0f * dimg[h * NFREQ + w];
            P[w] += A * ch - B * sh;
            Q[w] += A * sh + B * ch;
        }
    }
#pragma unroll
    for (int w = 0; w < NFREQ; ++w) {
        const float c = (w == 0 ? 1.0f : 2.0f) * (1.0f / 4096.0f);
        P[w] *= c; Q[w] *= c;
    }

    const int i0 = t * 16;
    const f32x4* wrow = (const f32x4*)(W + (size_t)o * IN_DIM + i0);
    float vals[16];
    float ss = 0.0f;

    const float beta0 = (TWO_PI / 4096.0f) * (float)i0;
    float cb = __cosf(beta0), sb = __sinf(beta0);

#pragma unroll
    for (int q = 0; q < 4; ++q) {
        const f32x4 wv = wrow[q];
#pragma unroll
        for (int j = 0; j < 4; ++j) {
            float cw = cb, sw = sb;
            float d = P[0] + P[1] * cw - Q[1] * sw;
#pragma unroll
            for (int w = 2; w < NFREQ; ++w) {
                const float cn = cw * cb - sw * sb;
                sw = sw * cb + cw * sb;
                cw = cn;
                d += P[w] * cw - Q[w] * sw;
            }
            const float v = wv[j] + d;
            vals[q * 4 + j] = v;
            ss += v * v;
            const float cbn = cb * ROT_C - sb * ROT_S;
            sb = sb * ROT_C + cb * ROT_S;
            cb = cbn;
        }
    }

#pragma unroll
    for (int off = 32; off > 0; off >>= 1)
        ss += __shfl_down(ss, off, 64);
    __shared__ float red[4];
    if ((t & 63) == 0) red[t >> 6] = ss;
    __syncthreads();
    const float n2 = red[0] + red[1] + red[2] + red[3];
    const float scale = mrow[o] / (sqrtf(n2) + 1e-8f);

    unsigned int wds[8];
#pragma unroll
    for (int k = 0; k < 8; ++k)
        wds[k] = f2bf(vals[2 * k] * scale) | (f2bf(vals[2 * k + 1] * scale) << 16);
    uint4* dst = (uint4*)(Wd + (size_t)o * IN_DIM + i0);
    dst[0] = make_uint4(wds[0], wds[1], wds[2], wds[3]);
    dst[1] = make_uint4(wds[4], wds[5], wds[6], wds[7]);
}

// ---------------------------------------------------------------------------
// 256x256-tile bf16 GEMM, 32x32x16 MFMA, barrier-minimal deep-prefetch.
//
// Same staging + 3-bit XOR swizzle + schedule as R4 (conflicts==0, ledger
// verified). Inner tiling now 32x32x16: per wave 4m x 2n tiles of 32x32,
// 8 MFMA per phase (256/K-tile/block vs 512 at 16x16x32), +15% MFMA-rate
// ceiling (2382 vs 2075 TF ubench).
//
// Operand lane maps (32x32x16 bf16):
//   A: lane l holds A[m=l&31][k = (l>>5)*8 + j]   (8 bf16, 4 VGPR)
//   B (N-major rows): lane l holds Wd[n=l&31][k = (l>>5)*8 + j]
//   C/D: col=lane&31, row=(reg&3)+8*(reg>>2)+4*(lane>>5)  [m74/m101]
// ds_read address: row r = base + (l&31); 16B chunk g = kg*2 + (l>>5),
// swizzled chunk = g ^ (r&7) = g ^ (l&7). Quarter-wave = 16 rows spanning
// all 8 chunk cols x2 lanes = 2-way (free).
//
// Schedule per K-tile t (buf b=t&1), 3 barriers/tile:
//   P1: rd a0(8) bb0(4) | STAGE Bh1(t+1)->b^1 | prio1 MFMA mt01xnt0 prio0
//   P2: rd a1(8)        |                     | prio1 MFMA mt23xnt0 prio0 | SBAR
//   P3: rd bb1(4)       | STAGE Ah0(t+2)->b   | prio1 MFMA mt23xnt1 prio0 | SBAR
//   P4: STAGE Ah1(t+2)->b; STAGE Bh0(t+2)->b  | prio1 MFMA mt01xnt1 prio0
//       | vmcnt(6) | SBAR
// vmcnt ledger: at P4 there are 14 outstanding (6 leftover t+1-halves +
// 2 B1(t+1) + 2 A0(t+2) + 4 A1/B0(t+2)); vmcnt(6) drains exactly tile
// t+1's 8 loads, leaving t+2's 6 in flight.
// ---------------------------------------------------------------------------

#define GLOAD(src, ldsoff)                                                    \
    __builtin_amdgcn_global_load_lds(                                         \
        (const __attribute__((address_space(1))) void*)(src),                 \
        (__attribute__((address_space(3))) void*)(smem + (ldsoff)), 16, 0, 0)

#define SBAR asm volatile("s_barrier" ::: "memory")

__global__ __launch_bounds__(512, 1) void gemm8_kernel(
    const unsigned short* __restrict__ Xb,
    const unsigned short* __restrict__ Wd,
    const float* __restrict__ bias,
    float* __restrict__ out)
{
    __shared__ __align__(1024) unsigned char smem[131072];

    const int tid = threadIdx.x;
    const int wid = tid >> 6, lane = tid & 63;
    const int wr = wid >> 2, wc = wid & 3;        // 2M x 4N waves
    const int ml = lane & 31;                     // m/n within 32-tile
    const int hk = lane >> 5;                     // k-half selector
    const int k7 = lane & 7;

    // XCD-aware block swizzle (512 blocks, 512%8==0 -> bijective)
    const int bid = blockIdx.x;
    const int lin = (bid & 7) * 64 + (bid >> 3);
    const int tm = lin & 31, tn = lin >> 5;
    const int m0 = tm * 256, n0 = tn * 256;

    // ---- staging coords: pre-swizzled global source, linear LDS dest ----
    const int srr = wid * 16 + (lane >> 3);                 // j=0 row in half
    const int scc = ((lane & 7) ^ (lane >> 3)) * 8;         // swizzled col (elems)
    const unsigned short* aS = Xb + (size_t)(m0 + srr) * IN_DIM + scc;
    const unsigned short* bS = Wd + (size_t)(n0 + srr) * IN_DIM + scc;
    const int sdst = wid * 2048;                            // + j*1024

    // ---- ds_read lane bases ----
    int co[4];
#pragma unroll
    for (int kg = 0; kg < 4; ++kg)
        co[kg] = (((kg * 2) | hk) ^ k7) * 16;
    const int aByte = (wr * 128 + ml) * 128;                  // + mt*4096
    const int bByte = LDS_B_REGION + (wc * 64 + ml) * 128;    // + nt*4096

    auto STAGE = [&](int buf, int isB, int half, int tt) {
        const unsigned short* s =
            (isB ? bS : aS) + (size_t)half * 128 * IN_DIM + (size_t)tt * BK;
        const int d = buf * LDS_BUF + isB * LDS_B_REGION + half * LDS_HALF + sdst;
        GLOAD(s, d);
        GLOAD(s + 8 * IN_DIM, d + 1024);
    };

    f32x16 acc[4][2] = {};
    bf16x8 a0[2][4], a1[2][4], bb[4];

    // ---- prologue: tile0 (4 halves) + tile1 (Ah0, Ah1, Bh0); Bh1(1) comes
    // from P1 of tile 0. Drain tile0's 8 loads: vmcnt(6). ----
    STAGE(0, 0, 0, 0); STAGE(0, 0, 1, 0);
    STAGE(0, 1, 0, 0); STAGE(0, 1, 1, 0);
    STAGE(1, 0, 0, 1); STAGE(1, 0, 1, 1);
    STAGE(1, 1, 0, 1);
    asm volatile("s_waitcnt vmcnt(6)" ::: "memory");
    SBAR;

    for (int t = 0; t < NT; ++t) {
        const int b = t & 1;
        const int bo = b * LDS_BUF;
        const bool st1 = (t + 1 < NT);
        const bool st2 = (t + 2 < NT);

        // ---------------- P1: mt0,1 x nt0 ----------------
#pragma unroll
        for (int i = 0; i < 2; ++i)
#pragma unroll
            for (int kg = 0; kg < 4; ++kg)
                a0[i][kg] = *(const bf16x8*)(smem + bo + aByte + i * 4096 + co[kg]);
#pragma unroll
        for (int kg = 0; kg < 4; ++kg)
            bb[kg] = *(const bf16x8*)(smem + bo + bByte + co[kg]);
        if (st1) STAGE(b ^ 1, 1, 1, t + 1);
        __builtin_amdgcn_s_setprio(1);
#pragma unroll
        for (int kg = 0; kg < 4; ++kg)
#pragma unroll
            for (int i = 0; i < 2; ++i)
                acc[i][0] = __builtin_amdgcn_mfma_f32_32x32x16_bf16(
                    a0[i][kg], bb[kg], acc[i][0], 0, 0, 0);
        __builtin_amdgcn_s_setprio(0);

        // ---------------- P2: mt2,3 x nt0 ----------------
#pragma unroll
        for (int i = 0; i < 2; ++i)
#pragma unroll
            for (int kg = 0; kg < 4; ++kg)
                a1[i][kg] = *(const bf16x8*)(smem + bo + aByte + 8192 + i * 4096 + co[kg]);
        __builtin_amdgcn_s_setprio(1);
#pragma unroll
        for (int kg = 0; kg < 4; ++kg)
#pragma unroll
            for (int i = 0; i < 2; ++i)
                acc[2 + i][0] = __builtin_amdgcn_mfma_f32_32x32x16_bf16(
                    a1[i][kg], bb[kg], acc[2 + i][0], 0, 0, 0);
        __builtin_amdgcn_s_setprio(0);
        SBAR;   // seals all A(t) reads -> A staging below may overwrite

        // ---------------- P3: mt2,3 x nt1 ----------------
#pragma unroll
        for (int kg = 0; kg < 4; ++kg)
            bb[kg] = *(const bf16x8*)(smem + bo + bByte + 4096 + co[kg]);
        if (st2) STAGE(b, 0, 0, t + 2);
        __builtin_amdgcn_s_setprio(1);
#pragma unroll
        for (int kg = 0; kg < 4; ++kg)
#pragma unroll
            for (int i = 0; i < 2; ++i)
                acc[2 + i][1] = __builtin_amdgcn_mfma_f32_32x32x16_bf16(
                    a1[i][kg], bb[kg], acc[2 + i][1], 0, 0, 0);
        __builtin_amdgcn_s_setprio(0);
        SBAR;   // seals all B(t) reads -> B staging below may overwrite

        // ---------------- P4: mt0,1 x nt1 ----------------
        if (st2) { STAGE(b, 0, 1, t + 2); STAGE(b, 1, 0, t + 2); }
        __builtin_amdgcn_s_setprio(1);
#pragma unroll
        for (int kg = 0; kg < 4; ++kg)
#pragma unroll
            for (int i = 0; i < 2; ++i)
                acc[i][1] = __builtin_amdgcn_mfma_f32_32x32x16_bf16(
                    a0[i][kg], bb[kg], acc[i][1], 0, 0, 0);
        __builtin_amdgcn_s_setprio(0);
        if (st2) {
            asm volatile("s_waitcnt vmcnt(6)" ::: "memory");
        } else {
            asm volatile("s_waitcnt vmcnt(0)" ::: "memory");
        }
        SBAR;   // tile boundary
    }

    // ---- epilogue: bias add + f32 store ----
    // C/D: col = lane&31, row = (reg&3) + 8*(reg>>2) + 4*hk
#pragma unroll
    for (int mt = 0; mt < 4; ++mt)
#pragma unroll
        for (int nt = 0; nt < 2; ++nt) {
            const int col = n0 + wc * 64 + nt * 32 + ml;
            const float bv = bias[col];
            const int row0 = m0 + wr * 128 + mt * 32 + hk * 4;
#pragma unroll
            for (int g = 0; g < 4; ++g) {
                float* op = out + (size_t)(row0 + g * 8) * OUT_DIM + col;
#pragma unroll
                for (int r = 0; r < 4; ++r)
                    op[(size_t)r * OUT_DIM] = acc[mt][nt][g * 4 + r] + bv;
            }
        }
}

// ---------------------------------------------------------------------------
// Fallback GEMM (128x128, reg-staged f32 A) — only if ws too small for Xb.
// ---------------------------------------------------------------------------
__global__ __launch_bounds__(256) void gemm_fallback(
    const float* __restrict__ Xf,
    const unsigned short* __restrict__ Wd,
    const float* __restrict__ bias,
    float* __restrict__ out)
{
    __shared__ unsigned short As[2][128 * 32];
    __shared__ unsigned short Bs[2][128 * 32];

    const int t = threadIdx.x;
    const int wid = t >> 6, lane = t & 63;
    const int wr = wid >> 1, wc = wid & 1;
    const int m0 = blockIdx.x * 128, n0 = blockIdx.y * 128;
    const int fr = lane & 15, fq = lane >> 4;

    f32x4 acc[4][4] = {};

    const int srow = wid * 16 + (lane >> 2);
    const int scol = (lane & 3) * 8;
    const unsigned short* bsrc0 = Wd + (size_t)(n0 + srow) * IN_DIM + scol;
    const unsigned short* bsrc1 = bsrc0 + (size_t)64 * IN_DIM;
    const int lds_off = wid * 512;

    const int ar = t >> 1;
    const int ak = (t & 1) * 16;
    const float* afp = Xf + (size_t)(m0 + ar) * IN_DIM + ak;
    const int a_lds_off = ar * 32 + ak;

    auto stageB = [&](unsigned short* ldsbase, int kt) {
        __builtin_amdgcn_global_load_lds(
            (const __attribute__((address_space(1))) void*)(bsrc0 + kt * 32),
            (__attribute__((address_space(3))) void*)(ldsbase + lds_off), 16, 0, 0);
        __builtin_amdgcn_global_load_lds(
            (const __attribute__((address_space(1))) void*)(bsrc1 + kt * 32),
            (__attribute__((address_space(3))) void*)(ldsbase + 2048 + lds_off), 16, 0, 0);
    };
    auto writeA = [&](int buf, const f32x4* v) {
        unsigned int w[8];
#pragma unroll
        for (int k = 0; k < 4; ++k) {
            w[2 * k]     = f2bf(v[k][0]) | (f2bf(v[k][1]) << 16);
            w[2 * k + 1] = f2bf(v[k][2]) | (f2bf(v[k][3]) << 16);
        }
        uint4* d = (uint4*)(&As[buf][a_lds_off]);
        d[0] = make_uint4(w[0], w[1], w[2], w[3]);
        d[1] = make_uint4(w[4], w[5], w[6], w[7]);
    };

    stageB(Bs[0], 0);
    {
        f32x4 av[4];
        const f32x4* ap = (const f32x4*)afp;
        av[0] = ap[0]; av[1] = ap[1]; av[2] = ap[2]; av[3] = ap[3];
        writeA(0, av);
    }
    __syncthreads();

    for (int kt = 0; kt < IN_DIM / 32; ++kt) {
        const int cur = kt & 1;
        const bool more = (kt + 1 < IN_DIM / 32);
        f32x4 nv[4];
        if (more) {
            const f32x4* ap = (const f32x4*)(afp + (size_t)(kt + 1) * 32);
            nv[0] = ap[0]; nv[1] = ap[1]; nv[2] = ap[2]; nv[3] = ap[3];
            stageB(Bs[cur ^ 1], kt + 1);
        }
        bf16x8 afrag[4], bfrag[4];
#pragma unroll
        for (int mf = 0; mf < 4; ++mf)
            afrag[mf] = *(const bf16x8*)(&As[cur][(wr * 64 + mf * 16 + fr) * 32 + fq * 8]);
#pragma unroll
        for (int nf = 0; nf < 4; ++nf)
            bfrag[nf] = *(const bf16x8*)(&Bs[cur][(wc * 64 + nf * 16 + fr) * 32 + fq * 8]);
#pragma unroll
        for (int mf = 0; mf < 4; ++mf)
#pragma unroll
            for (int nf = 0; nf < 4; ++nf)
                acc[mf][nf] = __builtin_amdgcn_mfma_f32_16x16x32_bf16(
                    afrag[mf], bfrag[nf], acc[mf][nf], 0, 0, 0);
        if (more) writeA(cur ^ 1, nv);
        __syncthreads();
    }

#pragma unroll
    for (int nf = 0; nf < 4; ++nf) {
        const int col = n0 + wc * 64 + nf * 16 + fr;
        const float bv = bias[col];
#pragma unroll
        for (int mf = 0; mf < 4; ++mf) {
            const int row = m0 + wr * 64 + mf * 16 + fq * 4;
            float* op = out + (size_t)row * OUT_DIM + col;
            op[0 * OUT_DIM] = acc[mf][nf][0] + bv;
            op[1 * OUT_DIM] = acc[mf][nf][1] + bv;
            op[2 * OUT_DIM] = acc[mf][nf][2] + bv;
            op[3 * OUT_DIM] = acc[mf][nf][3] + bv;
        }
    }
}

extern "C" void kernel_launch(void* const* d_in, const int* in_sizes, int n_in,
                              void* d_out, int out_size, void* d_ws, size_t ws_size,
                              hipStream_t stream) {
    const float* x    = (const float*)d_in[0];
    const float* W    = (const float*)d_in[1];
    const float* bias = (const float*)d_in[2];
    const float* dre  = (const float*)d_in[3];
    const float* dimg = (const float*)d_in[4];
    const float* mrow = (const float*)d_in[5];
    float* out = (float*)d_out;

    unsigned short* Wd = (unsigned short*)d_ws;
    const size_t WD_BYTES = (size_t)OUT_DIM * IN_DIM * 2;   // 32 MiB
    const size_t XB_BYTES = (size_t)MROWS * IN_DIM * 2;     // 64 MiB
    unsigned short* Xb = (unsigned short*)((char*)d_ws + WD_BYTES);
    const bool fast = ws_size >= WD_BYTES + XB_BYTES;

    if (fast) {
        const int cvt_blocks = (MROWS * (size_t)IN_DIM / 8) / 256;  // 16384
        prep_kernel<<<OUT_DIM + cvt_blocks, 256, 0, stream>>>(
            x, W, dre, dimg, mrow, Wd, Xb);
        gemm8_kernel<<<dim3((MROWS / 256) * (OUT_DIM / 256)), dim3(512), 0, stream>>>(
            Xb, Wd, bias, out);
    } else {
        prep_kernel<<<OUT_DIM, 256, 0, stream>>>(x, W, dre, dimg, mrow, Wd, Wd);
        dim3 grid(MROWS / 128, OUT_DIM / 128);
        gemm_fallback<<<grid, dim3(256), 0, stream>>>(x, Wd, bias, out);
    }
}

// Round 6
// 312.023 us; speedup vs baseline: 1.0816x; 1.0816x over previous
//
#include <hip/hip_runtime.h>
#include <hip/hip_bf16.h>

typedef __attribute__((ext_vector_type(4))) float f32x4;
typedef __attribute__((ext_vector_type(8))) short bf16x8;

#define IN_DIM 4096
#define OUT_DIM 4096
#define MROWS 8192   // B*S = 4*2048
#define NFREQ 8
#define TWO_PI 6.283185307179586f

#define BK 64
#define NT (IN_DIM / BK)        // 64 K-tiles
#define LDS_BUF 32768           // one operand buffer (256x64 bf16)
#define LDS_HALF 16384          // half buffer (128x64 bf16)
#define LDS_B_REGION 65536      // B region base byte

// f32 -> bf16 bits, round-to-nearest-even
__device__ __forceinline__ unsigned int f2bf(float f) {
    union { float f; unsigned int u; } a;
    a.f = f;
    unsigned int u = a.u;
    u += 0x7fffu + ((u >> 16) & 1u);
    return u >> 16;
}

// ---------------------------------------------------------------------------
// Fused prep kernel.
//  blocks [0, 4096):      dora rows — W_dora(bf16) = m*(W+irfft2(pad(delta)))/(||row||+eps)
//  blocks [4096, 20480):  x f32 -> bf16 cvt
// ---------------------------------------------------------------------------
#define ROT_C 0.9999988234517019f
#define ROT_S 0.0015339801862847655f

__global__ __launch_bounds__(256) void prep_kernel(
    const float* __restrict__ x,
    const float* __restrict__ W,
    const float* __restrict__ dre,
    const float* __restrict__ dimg,
    const float* __restrict__ mrow,
    unsigned short* __restrict__ Wd,
    unsigned short* __restrict__ xb)
{
    const int t = threadIdx.x;

    if (blockIdx.x >= OUT_DIM) {
        // ---- cvt branch ----
        const size_t idx = (size_t)(blockIdx.x - OUT_DIM) * 256 + t;
        const f32x4* p = (const f32x4*)(x + idx * 8);
        const f32x4 a = p[0], b = p[1];
        uint4 o;
        o.x = f2bf(a[0]) | (f2bf(a[1]) << 16);
        o.y = f2bf(a[2]) | (f2bf(a[3]) << 16);
        o.z = f2bf(b[0]) | (f2bf(b[1]) << 16);
        o.w = f2bf(b[2]) | (f2bf(b[3]) << 16);
        *(uint4*)(xb + idx * 8) = o;
        return;
    }

    // ---- dora branch ----
    const int o = blockIdx.x;

    float P[NFREQ], Q[NFREQ];
#pragma unroll
    for (int w = 0; w < NFREQ; ++w) { P[w] = 0.f; Q[w] = 0.f; }
#pragma unroll
    for (int h = 0; h < NFREQ; ++h) {
        const float th = (TWO_PI / 4096.0f) * (float)((h * o) & 4095);
        const float sh = __sinf(th), ch = __cosf(th);
#pragma unroll
        for (int w = 0; w < NFREQ; ++w) {
            const float A = 2.0f * dre[h * NFREQ + w];
            const float B = 2.0f * dimg[h * NFREQ + w];
            P[w] += A * ch - B * sh;
            Q[w] += A * sh + B * ch;
        }
    }
#pragma unroll
    for (int w = 0; w < NFREQ; ++w) {
        const float c = (w == 0 ? 1.0f : 2.0f) * (1.0f / 4096.0f);
        P[w] *= c; Q[w] *= c;
    }

    const int i0 = t * 16;
    const f32x4* wrow = (const f32x4*)(W + (size_t)o * IN_DIM + i0);
    float vals[16];
    float ss = 0.0f;

    const float beta0 = (TWO_PI / 4096.0f) * (float)i0;
    float cb = __cosf(beta0), sb = __sinf(beta0);

#pragma unroll
    for (int q = 0; q < 4; ++q) {
        const f32x4 wv = wrow[q];
#pragma unroll
        for (int j = 0; j < 4; ++j) {
            float cw = cb, sw = sb;
            float d = P[0] + P[1] * cw - Q[1] * sw;
#pragma unroll
            for (int w = 2; w < NFREQ; ++w) {
                const float cn = cw * cb - sw * sb;
                sw = sw * cb + cw * sb;
                cw = cn;
                d += P[w] * cw - Q[w] * sw;
            }
            const float v = wv[j] + d;
            vals[q * 4 + j] = v;
            ss += v * v;
            const float cbn = cb * ROT_C - sb * ROT_S;
            sb = sb * ROT_C + cb * ROT_S;
            cb = cbn;
        }
    }

#pragma unroll
    for (int off = 32; off > 0; off >>= 1)
        ss += __shfl_down(ss, off, 64);
    __shared__ float red[4];
    if ((t & 63) == 0) red[t >> 6] = ss;
    __syncthreads();
    const float n2 = red[0] + red[1] + red[2] + red[3];
    const float scale = mrow[o] / (sqrtf(n2) + 1e-8f);

    unsigned int wds[8];
#pragma unroll
    for (int k = 0; k < 8; ++k)
        wds[k] = f2bf(vals[2 * k] * scale) | (f2bf(vals[2 * k + 1] * scale) << 16);
    uint4* dst = (uint4*)(Wd + (size_t)o * IN_DIM + i0);
    dst[0] = make_uint4(wds[0], wds[1], wds[2], wds[3]);
    dst[1] = make_uint4(wds[4], wds[5], wds[6], wds[7]);
}

// ---------------------------------------------------------------------------
// 256x256-tile bf16 GEMM, 16x16x32 MFMA (R4 config: conflicts==0), now with
// compiler-scheduled lgkm chaining and 2 barriers/tile.
//
// LDS swizzle: slot (row rr, 16B-chunk c) holds global chunk c ^ (rr&7).
// Staging pre-swizzles the global source column (linear LDS dest);
// reads use chunk (g ^ (rr&7)) via cbyte/XOR-64 addressing. Measured 0
// bank conflicts (R3/R4).
//
// Schedule per K-tile t (buf b=t&1), 2 barriers/tile:
//   P1: rd a0(8)+bb0(4) | STAGE Bh1(t+1)->b^1 | prio1 MFMA(0,0) prio0
//   P2: rd a1(8)        |                     | prio1 MFMA(1,0) prio0
//   P3: rd bb1(4)       |                     | prio1 MFMA(1,1) prio0
//       | lgkmcnt(0) | SBAR
//   P4: STAGE Ah0,Ah1,Bh0(t+2)->b             | prio1 MFMA(0,1) prio0
//       | vmcnt(6) | lgkmcnt(0) | SBAR
//
// No explicit lgkm wait before MFMA clusters: all ds_reads are compiler-
// visible LDS loads, so hipcc emits fine-grained lgkmcnt(N) chaining
// (read k ready -> MFMA k issues while later reads still in flight).
// The lgkmcnt(0) BEFORE each sealing barrier guarantees every wave's
// reads have retired before any other wave's DMA may overwrite the
// region (closes the sink-past-barrier race; cost ~0, reads were
// consumed by the phase's MFMAs already).
//
// Write-after-read ledger (2-barrier version):
//   Bh1(t+1)->b^1 @P1(t): b^1 B reads (bb0@P1(t-1), bb1@P3(t-1)) retired
//     before lgkm0+SBAR@P3-end(t-1) < P4-end(t-1) < P1(t).  safe.
//   Ah0/Ah1/Bh0(t+2)->b @P4(t): ALL buf-b reads (a0,a1,bb0,bb1 of tile t)
//     retired before lgkm0+SBAR@P3-end(t); P4 stages are after it.  safe.
// vmcnt ledger: entering tile t: 6 outstanding (t+1 Ah0,Ah1,Bh0).
//   P1 +2 (Bh1 t+1) = 8.  P4 +6 (t+2) = 14; vmcnt(6) drains the oldest 8
//   = exactly tile t+1's full set, leaving t+2's 6 in flight.
//   Tail: st2==false -> vmcnt(0) drains everything before last tiles.
// ---------------------------------------------------------------------------

#define GLOAD(src, ldsoff)                                                    \
    __builtin_amdgcn_global_load_lds(                                         \
        (const __attribute__((address_space(1))) void*)(src),                 \
        (__attribute__((address_space(3))) void*)(smem + (ldsoff)), 16, 0, 0)

#define SBAR      asm volatile("s_barrier" ::: "memory")
#define WAITLGKM0 asm volatile("s_waitcnt lgkmcnt(0)" ::: "memory")

__device__ __forceinline__ void mfma16(
    f32x4 (&acc)[8][4], const bf16x8 (&af)[4][2], const bf16x8 (&bf)[2][2],
    int MH, int NH)
{
#pragma unroll
    for (int ks = 0; ks < 2; ++ks)
#pragma unroll
        for (int mf = 0; mf < 4; ++mf)
#pragma unroll
            for (int nf = 0; nf < 2; ++nf)
                acc[MH * 4 + mf][NH * 2 + nf] =
                    __builtin_amdgcn_mfma_f32_16x16x32_bf16(
                        af[mf][ks], bf[nf][ks], acc[MH * 4 + mf][NH * 2 + nf],
                        0, 0, 0);
}

__global__ __launch_bounds__(512, 1) void gemm8_kernel(
    const unsigned short* __restrict__ Xb,
    const unsigned short* __restrict__ Wd,
    const float* __restrict__ bias,
    float* __restrict__ out)
{
    __shared__ __align__(1024) unsigned char smem[131072];

    const int tid = threadIdx.x;
    const int wid = tid >> 6, lane = tid & 63;
    const int wr = wid >> 2, wc = wid & 3;        // 2M x 4N waves
    const int fr = lane & 15, fq = lane >> 4;

    // XCD-aware block swizzle (512 blocks, 512%8==0 -> bijective)
    const int bid = blockIdx.x;
    const int lin = (bid & 7) * 64 + (bid >> 3);
    const int tm = lin & 31, tn = lin >> 5;
    const int m0 = tm * 256, n0 = tn * 256;

    // ---- staging coords: pre-swizzled global source, linear LDS dest ----
    const int srr = wid * 16 + (lane >> 3);                 // j=0 row in half
    const int scc = ((lane & 7) ^ (lane >> 3)) * 8;         // swizzled col (elems)
    const unsigned short* aS = Xb + (size_t)(m0 + srr) * IN_DIM + scc;
    const unsigned short* bS = Wd + (size_t)(n0 + srr) * IN_DIM + scc;
    const int sdst = wid * 2048;                            // + j*1024

    // ---- ds_read lane bases (swizzled, per-ks via XOR 64) ----
    const int cbyte = ((fq ^ (fr & 7)) * 16);               // ks=0 chunk byte
    const int aBase0 = (wr * 128 + fr) * 128 + cbyte;       // + b*32768 + mh*8192 + mf*2048
    const int aBase1 = aBase0 ^ 64;                         // ks=1
    const int bBase0 = LDS_B_REGION + (wc * 64 + fr) * 128 + cbyte; // + b*32768 + nh*4096 + nf*2048
    const int bBase1 = bBase0 ^ 64;

    auto STAGE = [&](int buf, int isB, int half, int tt) {
        const unsigned short* s =
            (isB ? bS : aS) + (size_t)half * 128 * IN_DIM + (size_t)tt * BK;
        const int d = buf * LDS_BUF + isB * LDS_B_REGION + half * LDS_HALF + sdst;
        GLOAD(s, d);
        GLOAD(s + 8 * IN_DIM, d + 1024);
    };

    f32x4 acc[8][4] = {};
    bf16x8 a0[4][2], a1[4][2], bb[2][2];

    // ---- prologue: tile0 (4 halves) + tile1 (Ah0, Ah1, Bh0); Bh1(1) comes
    // from P1 of tile 0. Drain tile0's 8 loads: vmcnt(6). ----
    STAGE(0, 0, 0, 0); STAGE(0, 0, 1, 0);
    STAGE(0, 1, 0, 0); STAGE(0, 1, 1, 0);
    STAGE(1, 0, 0, 1); STAGE(1, 0, 1, 1);
    STAGE(1, 1, 0, 1);
    asm volatile("s_waitcnt vmcnt(6)" ::: "memory");
    SBAR;

    for (int t = 0; t < NT; ++t) {
        const int b = t & 1;
        const int bo = b * LDS_BUF;
        const bool st1 = (t + 1 < NT);   // stage Bh1(t+1)
        const bool st2 = (t + 2 < NT);   // stage A(t+2), Bh0(t+2)

        // ---------------- P1: MFMA quad (0,0) ----------------
#pragma unroll
        for (int mf = 0; mf < 4; ++mf) {
            a0[mf][0] = *(const bf16x8*)(smem + bo + aBase0 + mf * 2048);
            a0[mf][1] = *(const bf16x8*)(smem + bo + aBase1 + mf * 2048);
        }
#pragma unroll
        for (int nf = 0; nf < 2; ++nf) {
            bb[nf][0] = *(const bf16x8*)(smem + bo + bBase0 + nf * 2048);
            bb[nf][1] = *(const bf16x8*)(smem + bo + bBase1 + nf * 2048);
        }
        if (st1) STAGE(b ^ 1, 1, 1, t + 1);
        __builtin_amdgcn_s_setprio(1);
        mfma16(acc, a0, bb, 0, 0);
        __builtin_amdgcn_s_setprio(0);

        // ---------------- P2: MFMA quad (1,0) ----------------
#pragma unroll
        for (int mf = 0; mf < 4; ++mf) {
            a1[mf][0] = *(const bf16x8*)(smem + bo + aBase0 + 8192 + mf * 2048);
            a1[mf][1] = *(const bf16x8*)(smem + bo + aBase1 + 8192 + mf * 2048);
        }
        __builtin_amdgcn_s_setprio(1);
        mfma16(acc, a1, bb, 1, 0);
        __builtin_amdgcn_s_setprio(0);

        // ---------------- P3: MFMA quad (1,1) ----------------
#pragma unroll
        for (int nf = 0; nf < 2; ++nf) {
            bb[nf][0] = *(const bf16x8*)(smem + bo + bBase0 + 4096 + nf * 2048);
            bb[nf][1] = *(const bf16x8*)(smem + bo + bBase1 + 4096 + nf * 2048);
        }
        __builtin_amdgcn_s_setprio(1);
        mfma16(acc, a1, bb, 1, 1);
        __builtin_amdgcn_s_setprio(0);
        WAITLGKM0;   // all buf-b reads retired before signaling
        SBAR;        // seals ALL tile-t reads -> P4 stages may overwrite buf b

        // ---------------- P4: MFMA quad (0,1) ----------------
        if (st2) {
            STAGE(b, 0, 0, t + 2);
            STAGE(b, 0, 1, t + 2);
            STAGE(b, 1, 0, t + 2);
        }
        __builtin_amdgcn_s_setprio(1);
        mfma16(acc, a0, bb, 0, 1);
        __builtin_amdgcn_s_setprio(0);
        if (st2) {
            asm volatile("s_waitcnt vmcnt(6)" ::: "memory");
        } else {
            asm volatile("s_waitcnt vmcnt(0)" ::: "memory");
        }
        WAITLGKM0;
        SBAR;        // tile boundary: staged tile t+1 now visible to all
    }

    // ---- epilogue: bias add + f32 store ----
#pragma unroll
    for (int nf = 0; nf < 4; ++nf) {
        const int col = n0 + wc * 64 + nf * 16 + fr;
        const float bv = bias[col];
#pragma unroll
        for (int mf = 0; mf < 8; ++mf) {
            const int row = m0 + wr * 128 + mf * 16 + fq * 4;
            float* op = out + (size_t)row * OUT_DIM + col;
            op[0 * OUT_DIM] = acc[mf][nf][0] + bv;
            op[1 * OUT_DIM] = acc[mf][nf][1] + bv;
            op[2 * OUT_DIM] = acc[mf][nf][2] + bv;
            op[3 * OUT_DIM] = acc[mf][nf][3] + bv;
        }
    }
}

// ---------------------------------------------------------------------------
// Fallback GEMM (128x128, reg-staged f32 A) — only if ws too small for Xb.
// ---------------------------------------------------------------------------
__global__ __launch_bounds__(256) void gemm_fallback(
    const float* __restrict__ Xf,
    const unsigned short* __restrict__ Wd,
    const float* __restrict__ bias,
    float* __restrict__ out)
{
    __shared__ unsigned short As[2][128 * 32];
    __shared__ unsigned short Bs[2][128 * 32];

    const int t = threadIdx.x;
    const int wid = t >> 6, lane = t & 63;
    const int wr = wid >> 1, wc = wid & 1;
    const int m0 = blockIdx.x * 128, n0 = blockIdx.y * 128;
    const int fr = lane & 15, fq = lane >> 4;

    f32x4 acc[4][4] = {};

    const int srow = wid * 16 + (lane >> 2);
    const int scol = (lane & 3) * 8;
    const unsigned short* bsrc0 = Wd + (size_t)(n0 + srow) * IN_DIM + scol;
    const unsigned short* bsrc1 = bsrc0 + (size_t)64 * IN_DIM;
    const int lds_off = wid * 512;

    const int ar = t >> 1;
    const int ak = (t & 1) * 16;
    const float* afp = Xf + (size_t)(m0 + ar) * IN_DIM + ak;
    const int a_lds_off = ar * 32 + ak;

    auto stageB = [&](unsigned short* ldsbase, int kt) {
        __builtin_amdgcn_global_load_lds(
            (const __attribute__((address_space(1))) void*)(bsrc0 + kt * 32),
            (__attribute__((address_space(3))) void*)(ldsbase + lds_off), 16, 0, 0);
        __builtin_amdgcn_global_load_lds(
            (const __attribute__((address_space(1))) void*)(bsrc1 + kt * 32),
            (__attribute__((address_space(3))) void*)(ldsbase + 2048 + lds_off), 16, 0, 0);
    };
    auto writeA = [&](int buf, const f32x4* v) {
        unsigned int w[8];
#pragma unroll
        for (int k = 0; k < 4; ++k) {
            w[2 * k]     = f2bf(v[k][0]) | (f2bf(v[k][1]) << 16);
            w[2 * k + 1] = f2bf(v[k][2]) | (f2bf(v[k][3]) << 16);
        }
        uint4* d = (uint4*)(&As[buf][a_lds_off]);
        d[0] = make_uint4(w[0], w[1], w[2], w[3]);
        d[1] = make_uint4(w[4], w[5], w[6], w[7]);
    };

    stageB(Bs[0], 0);
    {
        f32x4 av[4];
        const f32x4* ap = (const f32x4*)afp;
        av[0] = ap[0]; av[1] = ap[1]; av[2] = ap[2]; av[3] = ap[3];
        writeA(0, av);
    }
    __syncthreads();

    for (int kt = 0; kt < IN_DIM / 32; ++kt) {
        const int cur = kt & 1;
        const bool more = (kt + 1 < IN_DIM / 32);
        f32x4 nv[4];
        if (more) {
            const f32x4* ap = (const f32x4*)(afp + (size_t)(kt + 1) * 32);
            nv[0] = ap[0]; nv[1] = ap[1]; nv[2] = ap[2]; nv[3] = ap[3];
            stageB(Bs[cur ^ 1], kt + 1);
        }
        bf16x8 afrag[4], bfrag[4];
#pragma unroll
        for (int mf = 0; mf < 4; ++mf)
            afrag[mf] = *(const bf16x8*)(&As[cur][(wr * 64 + mf * 16 + fr) * 32 + fq * 8]);
#pragma unroll
        for (int nf = 0; nf < 4; ++nf)
            bfrag[nf] = *(const bf16x8*)(&Bs[cur][(wc * 64 + nf * 16 + fr) * 32 + fq * 8]);
#pragma unroll
        for (int mf = 0; mf < 4; ++mf)
#pragma unroll
            for (int nf = 0; nf < 4; ++nf)
                acc[mf][nf] = __builtin_amdgcn_mfma_f32_16x16x32_bf16(
                    afrag[mf], bfrag[nf], acc[mf][nf], 0, 0, 0);
        if (more) writeA(cur ^ 1, nv);
        __syncthreads();
    }

#pragma unroll
    for (int nf = 0; nf < 4; ++nf) {
        const int col = n0 + wc * 64 + nf * 16 + fr;
        const float bv = bias[col];
#pragma unroll
        for (int mf = 0; mf < 4; ++mf) {
            const int row = m0 + wr * 64 + mf * 16 + fq * 4;
            float* op = out + (size_t)row * OUT_DIM + col;
            op[0 * OUT_DIM] = acc[mf][nf][0] + bv;
            op[1 * OUT_DIM] = acc[mf][nf][1] + bv;
            op[2 * OUT_DIM] = acc[mf][nf][2] + bv;
            op[3 * OUT_DIM] = acc[mf][nf][3] + bv;
        }
    }
}

extern "C" void kernel_launch(void* const* d_in, const int* in_sizes, int n_in,
                              void* d_out, int out_size, void* d_ws, size_t ws_size,
                              hipStream_t stream) {
    const float* x    = (const float*)d_in[0];
    const float* W    = (const float*)d_in[1];
    const float* bias = (const float*)d_in[2];
    const float* dre  = (const float*)d_in[3];
    const float* dimg = (const float*)d_in[4];
    const float* mrow = (const float*)d_in[5];
    float* out = (float*)d_out;

    unsigned short* Wd = (unsigned short*)d_ws;
    const size_t WD_BYTES = (size_t)OUT_DIM * IN_DIM * 2;   // 32 MiB
    const size_t XB_BYTES = (size_t)MROWS * IN_DIM * 2;     // 64 MiB
    unsigned short* Xb = (unsigned short*)((char*)d_ws + WD_BYTES);
    const bool fast = ws_size >= WD_BYTES + XB_BYTES;

    if (fast) {
        const int cvt_blocks = (MROWS * (size_t)IN_DIM / 8) / 256;  // 16384
        prep_kernel<<<OUT_DIM + cvt_blocks, 256, 0, stream>>>(
            x, W, dre, dimg, mrow, Wd, Xb);
        gemm8_kernel<<<dim3((MROWS / 256) * (OUT_DIM / 256)), dim3(512), 0, stream>>>(
            Xb, Wd, bias, out);
    } else {
        prep_kernel<<<OUT_DIM, 256, 0, stream>>>(x, W, dre, dimg, mrow, Wd, Wd);
        dim3 grid(MROWS / 128, OUT_DIM / 128);
        gemm_fallback<<<grid, dim3(256), 0, stream>>>(x, Wd, bias, out);
    }
}

// Round 7
// 289.311 us; speedup vs baseline: 1.1665x; 1.0785x over previous
//
#include <hip/hip_runtime.h>
#include <hip/hip_bf16.h>

typedef __attribute__((ext_vector_type(4))) float f32x4;
typedef __attribute__((ext_vector_type(8))) short bf16x8;

#define IN_DIM 4096
#define OUT_DIM 4096
#define MROWS 8192   // B*S = 4*2048
#define NFREQ 8
#define TWO_PI 6.283185307179586f

#define BK 64
#define NT (IN_DIM / BK)        // 64 K-tiles
#define LDS_BUF 32768           // one operand buffer (256x64 bf16)
#define LDS_HALF 16384          // half buffer (128x64 bf16)
#define LDS_B_REGION 65536      // B region base byte

// f32 -> bf16 bits, round-to-nearest-even
__device__ __forceinline__ unsigned int f2bf(float f) {
    union { float f; unsigned int u; } a;
    a.f = f;
    unsigned int u = a.u;
    u += 0x7fffu + ((u >> 16) & 1u);
    return u >> 16;
}

// ---------------------------------------------------------------------------
// Fused prep kernel.
//  blocks [0, 4096):      dora rows — W_dora(bf16) = m*(W+irfft2(pad(delta)))/(||row||+eps)
//  blocks [4096, 20480):  x f32 -> bf16 cvt
// ---------------------------------------------------------------------------
#define ROT_C 0.9999988234517019f
#define ROT_S 0.0015339801862847655f

__global__ __launch_bounds__(256) void prep_kernel(
    const float* __restrict__ x,
    const float* __restrict__ W,
    const float* __restrict__ dre,
    const float* __restrict__ dimg,
    const float* __restrict__ mrow,
    unsigned short* __restrict__ Wd,
    unsigned short* __restrict__ xb)
{
    const int t = threadIdx.x;

    if (blockIdx.x >= OUT_DIM) {
        // ---- cvt branch ----
        const size_t idx = (size_t)(blockIdx.x - OUT_DIM) * 256 + t;
        const f32x4* p = (const f32x4*)(x + idx * 8);
        const f32x4 a = p[0], b = p[1];
        uint4 o;
        o.x = f2bf(a[0]) | (f2bf(a[1]) << 16);
        o.y = f2bf(a[2]) | (f2bf(a[3]) << 16);
        o.z = f2bf(b[0]) | (f2bf(b[1]) << 16);
        o.w = f2bf(b[2]) | (f2bf(b[3]) << 16);
        *(uint4*)(xb + idx * 8) = o;
        return;
    }

    // ---- dora branch ----
    const int o = blockIdx.x;

    float P[NFREQ], Q[NFREQ];
#pragma unroll
    for (int w = 0; w < NFREQ; ++w) { P[w] = 0.f; Q[w] = 0.f; }
#pragma unroll
    for (int h = 0; h < NFREQ; ++h) {
        const float th = (TWO_PI / 4096.0f) * (float)((h * o) & 4095);
        const float sh = __sinf(th), ch = __cosf(th);
#pragma unroll
        for (int w = 0; w < NFREQ; ++w) {
            const float A = 2.0f * dre[h * NFREQ + w];
            const float B = 2.0f * dimg[h * NFREQ + w];
            P[w] += A * ch - B * sh;
            Q[w] += A * sh + B * ch;
        }
    }
#pragma unroll
    for (int w = 0; w < NFREQ; ++w) {
        const float c = (w == 0 ? 1.0f : 2.0f) * (1.0f / 4096.0f);
        P[w] *= c; Q[w] *= c;
    }

    const int i0 = t * 16;
    const f32x4* wrow = (const f32x4*)(W + (size_t)o * IN_DIM + i0);
    float vals[16];
    float ss = 0.0f;

    const float beta0 = (TWO_PI / 4096.0f) * (float)i0;
    float cb = __cosf(beta0), sb = __sinf(beta0);

#pragma unroll
    for (int q = 0; q < 4; ++q) {
        const f32x4 wv = wrow[q];
#pragma unroll
        for (int j = 0; j < 4; ++j) {
            float cw = cb, sw = sb;
            float d = P[0] + P[1] * cw - Q[1] * sw;
#pragma unroll
            for (int w = 2; w < NFREQ; ++w) {
                const float cn = cw * cb - sw * sb;
                sw = sw * cb + cw * sb;
                cw = cn;
                d += P[w] * cw - Q[w] * sw;
            }
            const float v = wv[j] + d;
            vals[q * 4 + j] = v;
            ss += v * v;
            const float cbn = cb * ROT_C - sb * ROT_S;
            sb = sb * ROT_C + cb * ROT_S;
            cb = cbn;
        }
    }

#pragma unroll
    for (int off = 32; off > 0; off >>= 1)
        ss += __shfl_down(ss, off, 64);
    __shared__ float red[4];
    if ((t & 63) == 0) red[t >> 6] = ss;
    __syncthreads();
    const float n2 = red[0] + red[1] + red[2] + red[3];
    const float scale = mrow[o] / (sqrtf(n2) + 1e-8f);

    unsigned int wds[8];
#pragma unroll
    for (int k = 0; k < 8; ++k)
        wds[k] = f2bf(vals[2 * k] * scale) | (f2bf(vals[2 * k + 1] * scale) << 16);
    uint4* dst = (uint4*)(Wd + (size_t)o * IN_DIM + i0);
    dst[0] = make_uint4(wds[0], wds[1], wds[2], wds[3]);
    dst[1] = make_uint4(wds[4], wds[5], wds[6], wds[7]);
}

// ---------------------------------------------------------------------------
// 256x256-tile bf16 GEMM, 16x16x32 MFMA, R4 3-barrier schedule (best
// measured: 252 us, conflicts==0) + paired-tn XCD swizzle for A-panel L2
// reuse + lgkm seals before the two sealing barriers.
//
// XCD swizzle: xcd = bid&7 gets u = bid>>3 in [0,64); tm = u>>1 (0..31),
// tn = 2*xcd + (u&1) (0..15). Bijective. The ~32 co-resident blocks per
// XCD are (tm 0..15) x (tn pair): each A-panel is read by TWO resident
// blocks (2nd read = L2 hit) and both B-panels (4 MB) fit the XCD L2.
// Old mapping had 32 distinct A-panels resident -> A streamed from HBM/L3.
//
// LDS swizzle: slot (row rr, 16B-chunk c) holds global chunk c ^ (rr&7);
// staging pre-swizzles the global source column (linear LDS dest); reads
// XOR the chunk index. Measured 0 bank conflicts.
//
// Schedule per K-tile t (buf b=t&1), 3 barriers/tile:
//   P1: rd a0(8)+bb0(4) | STAGE Bh1(t+1)->b^1 | prio1 MFMA(0,0) prio0
//   P2: rd a1(8)        |                     | prio1 MFMA(1,0) prio0
//       | lgkm0 | SBAR   (seals all A(t) reads)
//   P3: rd bb1(4)       | STAGE Ah0(t+2)->b   | prio1 MFMA(1,1) prio0
//       | lgkm0 | SBAR   (seals all B(t) reads)
//   P4: STAGE Ah1(t+2)->b; STAGE Bh0(t+2)->b  | prio1 MFMA(0,1) prio0
//       | vmcnt(6) | SBAR  (tile boundary)
//
// vmcnt ledger: entering tile t: 6 outstanding (t+1: Ah0,Ah1,Bh0).
//   P1 +2 (Bh1 t+1) = 8; P3 +2 (Ah0 t+2) = 10; P4 +4 = 14. vmcnt(6)
//   drains the oldest 8 = exactly tile t+1's full set. Tail: vmcnt(0).
// ---------------------------------------------------------------------------

#define GLOAD(src, ldsoff)                                                    \
    __builtin_amdgcn_global_load_lds(                                         \
        (const __attribute__((address_space(1))) void*)(src),                 \
        (__attribute__((address_space(3))) void*)(smem + (ldsoff)), 16, 0, 0)

#define SBAR      asm volatile("s_barrier" ::: "memory")
#define WAITLGKM0 asm volatile("s_waitcnt lgkmcnt(0)" ::: "memory")

__device__ __forceinline__ void mfma16(
    f32x4 (&acc)[8][4], const bf16x8 (&af)[4][2], const bf16x8 (&bf)[2][2],
    int MH, int NH)
{
#pragma unroll
    for (int ks = 0; ks < 2; ++ks)
#pragma unroll
        for (int mf = 0; mf < 4; ++mf)
#pragma unroll
            for (int nf = 0; nf < 2; ++nf)
                acc[MH * 4 + mf][NH * 2 + nf] =
                    __builtin_amdgcn_mfma_f32_16x16x32_bf16(
                        af[mf][ks], bf[nf][ks], acc[MH * 4 + mf][NH * 2 + nf],
                        0, 0, 0);
}

__global__ __launch_bounds__(512, 1) void gemm8_kernel(
    const unsigned short* __restrict__ Xb,
    const unsigned short* __restrict__ Wd,
    const float* __restrict__ bias,
    float* __restrict__ out)
{
    __shared__ __align__(1024) unsigned char smem[131072];

    const int tid = threadIdx.x;
    const int wid = tid >> 6, lane = tid & 63;
    const int wr = wid >> 2, wc = wid & 3;        // 2M x 4N waves
    const int fr = lane & 15, fq = lane >> 4;

    // paired-tn XCD swizzle (bijective: 512 blocks, 8 XCDs)
    const int bid = blockIdx.x;
    const int xcd = bid & 7;
    const int u = bid >> 3;                // [0,64) per XCD
    const int tm = u >> 1;                 // 0..31
    const int tn = 2 * xcd + (u & 1);      // 0..15
    const int m0 = tm * 256, n0 = tn * 256;

    // ---- staging coords: pre-swizzled global source, linear LDS dest ----
    const int srr = wid * 16 + (lane >> 3);                 // j=0 row in half
    const int scc = ((lane & 7) ^ (lane >> 3)) * 8;         // swizzled col (elems)
    const unsigned short* aS = Xb + (size_t)(m0 + srr) * IN_DIM + scc;
    const unsigned short* bS = Wd + (size_t)(n0 + srr) * IN_DIM + scc;
    const int sdst = wid * 2048;                            // + j*1024

    // ---- ds_read lane bases (swizzled, per-ks via XOR 64) ----
    const int cbyte = ((fq ^ (fr & 7)) * 16);               // ks=0 chunk byte
    const int aBase0 = (wr * 128 + fr) * 128 + cbyte;       // + b*32768 + mh*8192 + mf*2048
    const int aBase1 = aBase0 ^ 64;                         // ks=1
    const int bBase0 = LDS_B_REGION + (wc * 64 + fr) * 128 + cbyte; // + b*32768 + nh*4096 + nf*2048
    const int bBase1 = bBase0 ^ 64;

    auto STAGE = [&](int buf, int isB, int half, int tt) {
        const unsigned short* s =
            (isB ? bS : aS) + (size_t)half * 128 * IN_DIM + (size_t)tt * BK;
        const int d = buf * LDS_BUF + isB * LDS_B_REGION + half * LDS_HALF + sdst;
        GLOAD(s, d);
        GLOAD(s + 8 * IN_DIM, d + 1024);
    };

    f32x4 acc[8][4] = {};
    bf16x8 a0[4][2], a1[4][2], bb[2][2];

    // ---- prologue: tile0 (4 halves) + tile1 (Ah0, Ah1, Bh0); Bh1(1) comes
    // from P1 of tile 0. Drain tile0's 8 loads: vmcnt(6). ----
    STAGE(0, 0, 0, 0); STAGE(0, 0, 1, 0);
    STAGE(0, 1, 0, 0); STAGE(0, 1, 1, 0);
    STAGE(1, 0, 0, 1); STAGE(1, 0, 1, 1);
    STAGE(1, 1, 0, 1);
    asm volatile("s_waitcnt vmcnt(6)" ::: "memory");
    SBAR;

    for (int t = 0; t < NT; ++t) {
        const int b = t & 1;
        const int bo = b * LDS_BUF;
        const bool st1 = (t + 1 < NT);   // stage Bh1(t+1)
        const bool st2 = (t + 2 < NT);   // stage A(t+2), Bh0(t+2)

        // ---------------- P1: MFMA quad (0,0) ----------------
#pragma unroll
        for (int mf = 0; mf < 4; ++mf) {
            a0[mf][0] = *(const bf16x8*)(smem + bo + aBase0 + mf * 2048);
            a0[mf][1] = *(const bf16x8*)(smem + bo + aBase1 + mf * 2048);
        }
#pragma unroll
        for (int nf = 0; nf < 2; ++nf) {
            bb[nf][0] = *(const bf16x8*)(smem + bo + bBase0 + nf * 2048);
            bb[nf][1] = *(const bf16x8*)(smem + bo + bBase1 + nf * 2048);
        }
        if (st1) STAGE(b ^ 1, 1, 1, t + 1);
        __builtin_amdgcn_s_setprio(1);
        mfma16(acc, a0, bb, 0, 0);
        __builtin_amdgcn_s_setprio(0);

        // ---------------- P2: MFMA quad (1,0) ----------------
#pragma unroll
        for (int mf = 0; mf < 4; ++mf) {
            a1[mf][0] = *(const bf16x8*)(smem + bo + aBase0 + 8192 + mf * 2048);
            a1[mf][1] = *(const bf16x8*)(smem + bo + aBase1 + 8192 + mf * 2048);
        }
        __builtin_amdgcn_s_setprio(1);
        mfma16(acc, a1, bb, 1, 0);
        __builtin_amdgcn_s_setprio(0);
        WAITLGKM0;   // all A(t) fragment reads retired
        SBAR;        // seals A(t) -> P3/P4 A-stages may overwrite buf b A

        // ---------------- P3: MFMA quad (1,1) ----------------
#pragma unroll
        for (int nf = 0; nf < 2; ++nf) {
            bb[nf][0] = *(const bf16x8*)(smem + bo + bBase0 + 4096 + nf * 2048);
            bb[nf][1] = *(const bf16x8*)(smem + bo + bBase1 + 4096 + nf * 2048);
        }
        if (st2) STAGE(b, 0, 0, t + 2);
        __builtin_amdgcn_s_setprio(1);
        mfma16(acc, a1, bb, 1, 1);
        __builtin_amdgcn_s_setprio(0);
        WAITLGKM0;   // all B(t) fragment reads retired
        SBAR;        // seals B(t) -> P4 B-stage may overwrite buf b B

        // ---------------- P4: MFMA quad (0,1) ----------------
        if (st2) { STAGE(b, 0, 1, t + 2); STAGE(b, 1, 0, t + 2); }
        __builtin_amdgcn_s_setprio(1);
        mfma16(acc, a0, bb, 0, 1);
        __builtin_amdgcn_s_setprio(0);
        if (st2) {
            asm volatile("s_waitcnt vmcnt(6)" ::: "memory");
        } else {
            asm volatile("s_waitcnt vmcnt(0)" ::: "memory");
        }
        SBAR;   // tile boundary
    }

    // ---- epilogue: bias add + f32 store ----
#pragma unroll
    for (int nf = 0; nf < 4; ++nf) {
        const int col = n0 + wc * 64 + nf * 16 + fr;
        const float bv = bias[col];
#pragma unroll
        for (int mf = 0; mf < 8; ++mf) {
            const int row = m0 + wr * 128 + mf * 16 + fq * 4;
            float* op = out + (size_t)row * OUT_DIM + col;
            op[0 * OUT_DIM] = acc[mf][nf][0] + bv;
            op[1 * OUT_DIM] = acc[mf][nf][1] + bv;
            op[2 * OUT_DIM] = acc[mf][nf][2] + bv;
            op[3 * OUT_DIM] = acc[mf][nf][3] + bv;
        }
    }
}

// ---------------------------------------------------------------------------
// Fallback GEMM (128x128, reg-staged f32 A) — only if ws too small for Xb.
// ---------------------------------------------------------------------------
__global__ __launch_bounds__(256) void gemm_fallback(
    const float* __restrict__ Xf,
    const unsigned short* __restrict__ Wd,
    const float* __restrict__ bias,
    float* __restrict__ out)
{
    __shared__ unsigned short As[2][128 * 32];
    __shared__ unsigned short Bs[2][128 * 32];

    const int t = threadIdx.x;
    const int wid = t >> 6, lane = t & 63;
    const int wr = wid >> 1, wc = wid & 1;
    const int m0 = blockIdx.x * 128, n0 = blockIdx.y * 128;
    const int fr = lane & 15, fq = lane >> 4;

    f32x4 acc[4][4] = {};

    const int srow = wid * 16 + (lane >> 2);
    const int scol = (lane & 3) * 8;
    const unsigned short* bsrc0 = Wd + (size_t)(n0 + srow) * IN_DIM + scol;
    const unsigned short* bsrc1 = bsrc0 + (size_t)64 * IN_DIM;
    const int lds_off = wid * 512;

    const int ar = t >> 1;
    const int ak = (t & 1) * 16;
    const float* afp = Xf + (size_t)(m0 + ar) * IN_DIM + ak;
    const int a_lds_off = ar * 32 + ak;

    auto stageB = [&](unsigned short* ldsbase, int kt) {
        __builtin_amdgcn_global_load_lds(
            (const __attribute__((address_space(1))) void*)(bsrc0 + kt * 32),
            (__attribute__((address_space(3))) void*)(ldsbase + lds_off), 16, 0, 0);
        __builtin_amdgcn_global_load_lds(
            (const __attribute__((address_space(1))) void*)(bsrc1 + kt * 32),
            (__attribute__((address_space(3))) void*)(ldsbase + 2048 + lds_off), 16, 0, 0);
    };
    auto writeA = [&](int buf, const f32x4* v) {
        unsigned int w[8];
#pragma unroll
        for (int k = 0; k < 4; ++k) {
            w[2 * k]     = f2bf(v[k][0]) | (f2bf(v[k][1]) << 16);
            w[2 * k + 1] = f2bf(v[k][2]) | (f2bf(v[k][3]) << 16);
        }
        uint4* d = (uint4*)(&As[buf][a_lds_off]);
        d[0] = make_uint4(w[0], w[1], w[2], w[3]);
        d[1] = make_uint4(w[4], w[5], w[6], w[7]);
    };

    stageB(Bs[0], 0);
    {
        f32x4 av[4];
        const f32x4* ap = (const f32x4*)afp;
        av[0] = ap[0]; av[1] = ap[1]; av[2] = ap[2]; av[3] = ap[3];
        writeA(0, av);
    }
    __syncthreads();

    for (int kt = 0; kt < IN_DIM / 32; ++kt) {
        const int cur = kt & 1;
        const bool more = (kt + 1 < IN_DIM / 32);
        f32x4 nv[4];
        if (more) {
            const f32x4* ap = (const f32x4*)(afp + (size_t)(kt + 1) * 32);
            nv[0] = ap[0]; nv[1] = ap[1]; nv[2] = ap[2]; nv[3] = ap[3];
            stageB(Bs[cur ^ 1], kt + 1);
        }
        bf16x8 afrag[4], bfrag[4];
#pragma unroll
        for (int mf = 0; mf < 4; ++mf)
            afrag[mf] = *(const bf16x8*)(&As[cur][(wr * 64 + mf * 16 + fr) * 32 + fq * 8]);
#pragma unroll
        for (int nf = 0; nf < 4; ++nf)
            bfrag[nf] = *(const bf16x8*)(&Bs[cur][(wc * 64 + nf * 16 + fr) * 32 + fq * 8]);
#pragma unroll
        for (int mf = 0; mf < 4; ++mf)
#pragma unroll
            for (int nf = 0; nf < 4; ++nf)
                acc[mf][nf] = __builtin_amdgcn_mfma_f32_16x16x32_bf16(
                    afrag[mf], bfrag[nf], acc[mf][nf], 0, 0, 0);
        if (more) writeA(cur ^ 1, nv);
        __syncthreads();
    }

#pragma unroll
    for (int nf = 0; nf < 4; ++nf) {
        const int col = n0 + wc * 64 + nf * 16 + fr;
        const float bv = bias[col];
#pragma unroll
        for (int mf = 0; mf < 4; ++mf) {
            const int row = m0 + wr * 64 + mf * 16 + fq * 4;
            float* op = out + (size_t)row * OUT_DIM + col;
            op[0 * OUT_DIM] = acc[mf][nf][0] + bv;
            op[1 * OUT_DIM] = acc[mf][nf][1] + bv;
            op[2 * OUT_DIM] = acc[mf][nf][2] + bv;
            op[3 * OUT_DIM] = acc[mf][nf][3] + bv;
        }
    }
}

extern "C" void kernel_launch(void* const* d_in, const int* in_sizes, int n_in,
                              void* d_out, int out_size, void* d_ws, size_t ws_size,
                              hipStream_t stream) {
    const float* x    = (const float*)d_in[0];
    const float* W    = (const float*)d_in[1];
    const float* bias = (const float*)d_in[2];
    const float* dre  = (const float*)d_in[3];
    const float* dimg = (const float*)d_in[4];
    const float* mrow = (const float*)d_in[5];
    float* out = (float*)d_out;

    unsigned short* Wd = (unsigned short*)d_ws;
    const size_t WD_BYTES = (size_t)OUT_DIM * IN_DIM * 2;   // 32 MiB
    const size_t XB_BYTES = (size_t)MROWS * IN_DIM * 2;     // 64 MiB
    unsigned short* Xb = (unsigned short*)((char*)d_ws + WD_BYTES);
    const bool fast = ws_size >= WD_BYTES + XB_BYTES;

    if (fast) {
        const int cvt_blocks = (MROWS * (size_t)IN_DIM / 8) / 256;  // 16384
        prep_kernel<<<OUT_DIM + cvt_blocks, 256, 0, stream>>>(
            x, W, dre, dimg, mrow, Wd, Xb);
        gemm8_kernel<<<dim3((MROWS / 256) * (OUT_DIM / 256)), dim3(512), 0, stream>>>(
            Xb, Wd, bias, out);
    } else {
        prep_kernel<<<OUT_DIM, 256, 0, stream>>>(x, W, dre, dimg, mrow, Wd, Wd);
        dim3 grid(MROWS / 128, OUT_DIM / 128);
        gemm_fallback<<<grid, dim3(256), 0, stream>>>(x, Wd, bias, out);
    }
}